// Round 8
// baseline (1226.821 us; speedup 1.0000x reference)
//
#include <hip/hip_runtime.h>

typedef unsigned short u16;
typedef __attribute__((ext_vector_type(8))) short short8;
typedef __attribute__((ext_vector_type(4))) float f32x4;

#define DEVI static __device__ __forceinline__

DEVI u16 f2bf(float f) {
  union { float f; unsigned u; } v; v.f = f;
  unsigned r = v.u + 0x7FFFu + ((v.u >> 16) & 1u);
  return (u16)(r >> 16);
}

DEVI short8 pack8(float4 a, float4 b) {
  short8 v;
  v[0] = (short)f2bf(a.x); v[1] = (short)f2bf(a.y);
  v[2] = (short)f2bf(a.z); v[3] = (short)f2bf(a.w);
  v[4] = (short)f2bf(b.x); v[5] = (short)f2bf(b.y);
  v[6] = (short)f2bf(b.z); v[7] = (short)f2bf(b.w);
  return v;
}

DEVI float sigm(float x) {
  return __builtin_amdgcn_rcpf(1.f + __expf(-x));
}
DEVI float tanh_(float x) {
  // 1 - 2/(exp(2x)+1); correct limits at +-inf
  return 1.f - 2.f * __builtin_amdgcn_rcpf(__expf(2.f * x) + 1.f);
}

// ---------------------------------------------------------------------------
// Prep (v2 original, measured in the 516us run): coalesced reads.
//   Ut[1024][256] <- U(256,1024)   Wt[1024][128] <- W(128,1024)
//   w2t[64][512]  <- w2_k(512,64)
// ---------------------------------------------------------------------------
__global__ __launch_bounds__(256) void k_prep(
    const float* __restrict__ W, const float* __restrict__ U,
    const float* __restrict__ w2k, u16* __restrict__ Wt,
    u16* __restrict__ Ut, u16* __restrict__ w2t) {
  int idx = blockIdx.x * 256 + threadIdx.x;
  int stride = gridDim.x * 256;
  for (int i = idx; i < 256 * 1024; i += stride) {
    int k = i >> 10, j = i & 1023;
    Ut[j * 256 + k] = f2bf(U[i]);
  }
  for (int i = idx; i < 128 * 1024; i += stride) {
    int k = i >> 10, j = i & 1023;
    Wt[j * 128 + k] = f2bf(W[i]);
  }
  for (int i = idx; i < 512 * 64; i += stride) {
    int k = i >> 6, s = i & 63;
    w2t[s * 512 + k] = f2bf(w2k[i]);
  }
}

// ---------------------------------------------------------------------------
// Phase A scan v4 = v2 dataflow, 16 waves (1024 thr) instead of 8.
// Wave w (0..15) owns hidden units m in [16w, 16w+16) across all 4 gates.
// Same two barriers, same LDS, same in-loop load pattern as the measured v2
// (compiler-scheduled loads — no hand pipelining, no anti-LICM games).
// Waves 0-3 compute q post-barrier; waves 4-7 prefetch x_{t+1}.
// ---------------------------------------------------------------------------
__global__ __launch_bounds__(1024, 4) void k_lstm(
    const float* __restrict__ data, const float* __restrict__ h0,
    const float* __restrict__ c0, const float* __restrict__ bias,
    const float* __restrict__ w2b, const u16* __restrict__ Wt,
    const u16* __restrict__ Ut, const u16* __restrict__ w2t,
    float* __restrict__ QS) {
  __shared__ u16 Xs[16][136];     // x_t bf16 (pad 128->136)
  __shared__ u16 Hs[2][16][264];  // h ping-pong (pad 256->264)
  __shared__ u16 Cs[16][264];     // c2 of current step

  const int tid = threadIdx.x;
  const int lane = tid & 63;
  const int w = tid >> 6;         // wave 0..15
  const int l15 = lane & 15;
  const int l4 = lane >> 4;       // 0..3
  const int b0 = blockIdx.x << 4;

  // Stage x_0 (threads 0-255) and h_0 (threads 256-511)
  if (tid < 256) {
    int row = tid >> 4, cb = (tid & 15) * 8;
    const float4* p =
        reinterpret_cast<const float4*>(&data[(size_t)(b0 + row) * 8192 + cb]);
    float4 a = p[0], b = p[1];
    *reinterpret_cast<short8*>(&Xs[row][cb]) = pack8(a, b);
  } else if (tid < 512) {
    int t2 = tid - 256;
    int row = t2 >> 4, hb = (t2 & 15) * 16;
    const float4* p =
        reinterpret_cast<const float4*>(&h0[(size_t)(b0 + row) * 256 + hb]);
    float4 a0 = p[0], a1 = p[1], a2 = p[2], a3 = p[3];
    *reinterpret_cast<short8*>(&Hs[0][row][hb]) = pack8(a0, a1);
    *reinterpret_cast<short8*>(&Hs[0][row][hb + 8]) = pack8(a2, a3);
  }

  // c state fp32 in registers: lane owns (batch=l4*4+r, m=16w+l15)
  float creg[4];
#pragma unroll
  for (int r = 0; r < 4; ++r)
    creg[r] = c0[(size_t)(b0 + l4 * 4 + r) * 256 + w * 16 + l15];

  float bz[4];
#pragma unroll
  for (int g = 0; g < 4; ++g) bz[g] = bias[g * 256 + w * 16 + l15];

  const float w2bv = (w < 4) ? w2b[w * 16 + l15] : 0.f;

  __syncthreads();

  for (int t = 0; t < 64; ++t) {
    const int cur = t & 1, nxt = cur ^ 1;

    // z = [x_t | h] @ [Wt;Ut] + b   (MFMA, K=384; compiler-scheduled loads)
    f32x4 acc[4];
#pragma unroll
    for (int g = 0; g < 4; ++g)
      acc[g] = (f32x4){bz[g], bz[g], bz[g], bz[g]};

#pragma unroll
    for (int kk = 0; kk < 12; ++kk) {
      short8 af;
      if (kk < 4)
        af = *reinterpret_cast<const short8*>(&Xs[l15][kk * 32 + l4 * 8]);
      else
        af = *reinterpret_cast<const short8*>(
            &Hs[cur][l15][(kk - 4) * 32 + l4 * 8]);
#pragma unroll
      for (int g = 0; g < 4; ++g) {
        const int col = g * 256 + w * 16 + l15;
        short8 bf;
        if (kk < 4)
          bf = *reinterpret_cast<const short8*>(
              &Wt[col * 128 + kk * 32 + l4 * 8]);
        else
          bf = *reinterpret_cast<const short8*>(
              &Ut[(size_t)col * 256 + (kk - 4) * 32 + l4 * 8]);
        acc[g] =
            __builtin_amdgcn_mfma_f32_16x16x32_bf16(af, bf, acc[g], 0, 0, 0);
      }
    }

    // Gates (lane-local), update c, write h2/c2 bf16 for next step / q
#pragma unroll
    for (int r = 0; r < 4; ++r) {
      float iv = sigm(acc[0][r]);
      float fv = sigm(acc[1][r]);
      float gv = tanh_(acc[2][r]);
      float ov = sigm(acc[3][r]);
      float c2 = fv * creg[r] + iv * gv;
      creg[r] = c2;
      float h2 = ov * tanh_(c2);
      int m = w * 16 + l15;
      int br = l4 * 4 + r;
      Hs[nxt][br][m] = f2bf(h2);
      Cs[br][m] = f2bf(c2);
    }
    __syncthreads();

    if (w < 4) {
      // q = [h2|c2] @ w2_k + w2_b  -> QS[t]
      f32x4 qa = (f32x4){w2bv, w2bv, w2bv, w2bv};
      const int colq = w * 16 + l15;
#pragma unroll
      for (int kk = 0; kk < 16; ++kk) {
        short8 af;
        if (kk < 8)
          af = *reinterpret_cast<const short8*>(
              &Hs[nxt][l15][kk * 32 + l4 * 8]);
        else
          af = *reinterpret_cast<const short8*>(
              &Cs[l15][(kk - 8) * 32 + l4 * 8]);
        short8 bf = *reinterpret_cast<const short8*>(
            &w2t[colq * 512 + kk * 32 + l4 * 8]);
        qa = __builtin_amdgcn_mfma_f32_16x16x32_bf16(af, bf, qa, 0, 0, 0);
      }
#pragma unroll
      for (int r = 0; r < 4; ++r)
        QS[(size_t)(t * 128 + b0 + l4 * 4 + r) * 64 + w * 16 + l15] = qa[r];
    } else if (w < 8 && t < 63) {
      // waves 4-7: prefetch x_{t+1}
      int t2 = tid - 256;
      int row = t2 >> 4, cb = (t2 & 15) * 8;
      const float4* p = reinterpret_cast<const float4*>(
          &data[(size_t)(b0 + row) * 8192 + (t + 1) * 128 + cb]);
      float4 a = p[0], b = p[1];
      *reinterpret_cast<short8*>(&Xs[row][cb]) = pack8(a, b);
    }
    __syncthreads();
  }
}

// ---------------------------------------------------------------------------
// Phase B: attention (unchanged from measured v2).
// out_flat[P*128+f] = data_flat[P*128+f] * alpha(t=P>>7, b=P&127), P=t*128+b.
// ---------------------------------------------------------------------------
__global__ __launch_bounds__(256) void k_attn(
    const float* __restrict__ data, const float* __restrict__ w1k,
    const float* __restrict__ w1b, const float* __restrict__ vk,
    const float* __restrict__ vb, const float* __restrict__ QS,
    float* __restrict__ out) {
  __shared__ float Xs[64][128];
  __shared__ float Wk[64][64];
  __shared__ float w1x[128][66];
  __shared__ float vls[64];
  __shared__ float qls[2][64];
  __shared__ float red[4][2];

  const int tid = threadIdx.x;
  const int b = blockIdx.x >> 1;
  const int half = blockIdx.x & 1;

#pragma unroll
  for (int c = 0; c < 8; ++c) {
    int i = c * 1024 + tid * 4;
    *reinterpret_cast<float4*>(&Xs[0][0] + i) =
        *reinterpret_cast<const float4*>(&data[(size_t)b * 8192 + i]);
  }
#pragma unroll
  for (int c = 0; c < 4; ++c) {
    int i = c * 1024 + tid * 4;
    *reinterpret_cast<float4*>(&Wk[0][0] + i) =
        *reinterpret_cast<const float4*>(&w1k[i]);
  }
  if (tid < 64) vls[tid] = vk[tid];
  __syncthreads();

  const int f = tid & 127;
  const int sh = tid >> 7;
  const int s0 = sh * 32;
  {
    float a[32];
#pragma unroll
    for (int j = 0; j < 32; ++j) a[j] = w1b[s0 + j];
    for (int t = 0; t < 64; ++t) {
      float xv = Xs[t][f];
#pragma unroll
      for (int j = 0; j < 32; ++j) a[j] = __fmaf_rn(xv, Wk[t][s0 + j], a[j]);
    }
#pragma unroll
    for (int j = 0; j < 32; ++j) w1x[f][s0 + j] = a[j];
  }
  __syncthreads();

  const float vbv = vb[0];
  const int wv = tid >> 6;
  const int lane = tid & 63;

  for (int tt = 0; tt < 16; ++tt) {
    if (tid < 128) {
      int which = tid >> 6, s = tid & 63;
      qls[which][s] =
          QS[(size_t)((half * 32 + tt * 2 + which) * 128 + b) * 64 + s];
    }
    __syncthreads();

    float acc = vbv;
#pragma unroll 8
    for (int s = 0; s < 64; ++s)
      acc += tanh_(w1x[f][s] + qls[sh][s]) * vls[s];

    float m = acc;
#pragma unroll
    for (int o = 32; o > 0; o >>= 1) m = fmaxf(m, __shfl_xor(m, o));
    if (lane == 0) red[wv][0] = m;
    __syncthreads();
    m = fmaxf(red[sh * 2][0], red[sh * 2 + 1][0]);
    float e = __expf(acc - m);
    float sum = e;
#pragma unroll
    for (int o = 32; o > 0; o >>= 1) sum += __shfl_xor(sum, o);
    if (lane == 0) red[wv][1] = sum;
    __syncthreads();
    sum = red[sh * 2][1] + red[sh * 2 + 1][1];
    float alpha = e / sum;

    int t = half * 32 + tt * 2 + sh;
    size_t P = (size_t)t * 128 + b;
    out[P * 128 + f] = data[P * 128 + f] * alpha;
    __syncthreads();
  }
}

// ---------------------------------------------------------------------------
extern "C" void kernel_launch(void* const* d_in, const int* in_sizes, int n_in,
                              void* d_out, int out_size, void* d_ws,
                              size_t ws_size, hipStream_t stream) {
  (void)in_sizes; (void)n_in; (void)out_size; (void)ws_size;
  const float* data = (const float*)d_in[0];
  const float* h0   = (const float*)d_in[1];
  const float* c0   = (const float*)d_in[2];
  const float* W    = (const float*)d_in[3];
  const float* U    = (const float*)d_in[4];
  const float* bias = (const float*)d_in[5];
  const float* w1k  = (const float*)d_in[6];
  const float* w1b  = (const float*)d_in[7];
  const float* w2k  = (const float*)d_in[8];
  const float* w2b  = (const float*)d_in[9];
  const float* vk   = (const float*)d_in[10];
  const float* vb   = (const float*)d_in[11];
  float* out = (float*)d_out;

  char* ws = (char*)d_ws;
  u16* Ut   = (u16*)(ws);            // 512 KB
  u16* Wt   = (u16*)(ws + 524288);   // 256 KB
  u16* w2t  = (u16*)(ws + 786432);   //  64 KB
  float* QS = (float*)(ws + 851968); //   2 MB

  k_prep<<<512, 256, 0, stream>>>(W, U, w2k, Wt, Ut, w2t);
  k_lstm<<<8, 1024, 0, stream>>>(data, h0, c0, bias, w2b, Wt, Ut, w2t, QS);
  k_attn<<<256, 256, 0, stream>>>(data, w1k, w1b, vk, vb, QS, out);
}

// Round 10
// 623.811 us; speedup vs baseline: 1.9667x; 1.9667x over previous
//
#include <hip/hip_runtime.h>

typedef unsigned short u16;
typedef unsigned long long u64;
typedef __attribute__((ext_vector_type(8))) short short8;
typedef __attribute__((ext_vector_type(4))) float f32x4;

#define DEVI static __device__ __forceinline__
#define FLAG_BASE 0x1B000000

DEVI u16 f2bf(float f) {
  union { float f; unsigned u; } v; v.f = f;
  unsigned r = v.u + 0x7FFFu + ((v.u >> 16) & 1u);
  return (u16)(r >> 16);
}

DEVI unsigned cvt_pk_bf16(float lo, float hi) {
  unsigned r;
  asm("v_cvt_pk_bf16_f32 %0, %1, %2" : "=v"(r) : "v"(lo), "v"(hi));
  return r;  // [15:0]=bf16(lo), [31:16]=bf16(hi)
}

DEVI short8 pack8(float4 a, float4 b) {
  short8 v;
  v[0] = (short)f2bf(a.x); v[1] = (short)f2bf(a.y);
  v[2] = (short)f2bf(a.z); v[3] = (short)f2bf(a.w);
  v[4] = (short)f2bf(b.x); v[5] = (short)f2bf(b.y);
  v[6] = (short)f2bf(b.z); v[7] = (short)f2bf(b.w);
  return v;
}

DEVI float sigm(float x) {
  return __builtin_amdgcn_rcpf(1.f + __expf(-x));
}
DEVI float tanh_(float x) {
  return 1.f - 2.f * __builtin_amdgcn_rcpf(__expf(2.f * x) + 1.f);
}

// ---------------------------------------------------------------------------
// Prep: transposed bf16 weights, coalesced writes.
//   Ut[1024][256] <- U(256,1024)   Wt[1024][128] <- W(128,1024)
//   w2t[64][512]  <- w2_k(512,64)
// ---------------------------------------------------------------------------
__global__ __launch_bounds__(256) void k_prep(
    const float* __restrict__ W, const float* __restrict__ U,
    const float* __restrict__ w2k, u16* __restrict__ Wt,
    u16* __restrict__ Ut, u16* __restrict__ w2t) {
  int idx = blockIdx.x * 256 + threadIdx.x;
  int stride = gridDim.x * 256;
  for (int o = idx; o < 256 * 1024; o += stride) {
    int j = o >> 8, k = o & 255;
    Ut[o] = f2bf(U[k * 1024 + j]);
  }
  for (int o = idx; o < 128 * 1024; o += stride) {
    int j = o >> 7, k = o & 127;
    Wt[o] = f2bf(W[k * 1024 + j]);
  }
  for (int o = idx; o < 64 * 512; o += stride) {
    int s = o >> 9, k = o & 511;
    w2t[o] = f2bf(w2k[k * 64 + s]);
  }
}

// ---------------------------------------------------------------------------
// v5 cooperative scan. Grid 32 = ms(0..3) * 8 + bg(0..7)  [partners same XCD
// under %8 round-robin; correctness independent of placement].
// Block (bg, ms): batches [bg*16,+16), z-cols {g*256 + ms*64 + 0..63, g=0..3}.
// W/U slices live in REGISTERS (wf 32 + uf 64 VGPR/wave) -> zero weight
// traffic in the loop. Per step: MFMA z -> Zs -> gate combine (c in regs) ->
// h2/c2 slice to HC (device-scope) + flag -> spin partners -> pull 6KB h2.
// q is NOT computed here (deferred to k_qs; it never feeds the recurrence).
// ---------------------------------------------------------------------------
__global__ __launch_bounds__(512, 2) void k_scan(
    const float* __restrict__ data, const float* __restrict__ h0,
    const float* __restrict__ c0, const float* __restrict__ bias,
    const u16* __restrict__ Wt, const u16* __restrict__ Ut,
    u16* __restrict__ HC, int* __restrict__ flags) {
  __shared__ u16 Xs[16][136];    // x_t bf16
  __shared__ u16 Hs[16][264];    // full h (single buffer; barrier-protected)
  __shared__ float Zs[16][273];  // z tile fp32 (padded: 273%32=17)

  const int tid = threadIdx.x;
  const int lane = tid & 63;
  const int w = tid >> 6;        // wave 0..7
  const int l15 = lane & 15;
  const int l4 = lane >> 4;      // 0..3
  const int ms = blockIdx.x >> 3;  // m-slice 0..3
  const int bg = blockIdx.x & 7;   // batch group 0..7
  const int b0 = bg << 4;

  // --- stage x_0 (threads 0..127) and full h_0 (threads 128..383) ---
  if (tid < 128) {
    int row = tid >> 3, seg = tid & 7;
    const float4* p = reinterpret_cast<const float4*>(
        &data[(size_t)(b0 + row) * 8192 + seg * 16]);
    float4 a0 = p[0], a1 = p[1], a2 = p[2], a3 = p[3];
    *reinterpret_cast<short8*>(&Xs[row][seg * 16]) = pack8(a0, a1);
    *reinterpret_cast<short8*>(&Xs[row][seg * 16 + 8]) = pack8(a2, a3);
  } else if (tid < 384) {
    int k = tid - 128;
    int row = k >> 4, ch = k & 15;
    const float4* p = reinterpret_cast<const float4*>(
        &h0[(size_t)(b0 + row) * 256 + ch * 16]);
    float4 a0 = p[0], a1 = p[1], a2 = p[2], a3 = p[3];
    *reinterpret_cast<short8*>(&Hs[row][ch * 16]) = pack8(a0, a1);
    *reinterpret_cast<short8*>(&Hs[row][ch * 16 + 8]) = pack8(a2, a3);
  }

  // --- c state fp32: combine-thread tid owns (b=tid&15, m_l=2*(tid>>4)+e) ---
  float creg[2];
  {
    int b = tid & 15, mi = tid >> 4;
    creg[0] = c0[(size_t)(b0 + b) * 256 + ms * 64 + mi * 2];
    creg[1] = c0[(size_t)(b0 + b) * 256 + ms * 64 + mi * 2 + 1];
  }

  // --- weight slices into registers: wave w -> frags fi=w*2+f ---
  short8 uf[2][8];  // h@U  (64 VGPR)
  short8 wf[2][4];  // x@W  (32 VGPR)
  float bz[2];
#pragma unroll
  for (int f = 0; f < 2; ++f) {
    const int fi = w * 2 + f;
    const int col = (fi & 3) * 256 + ms * 64 + (fi >> 2) * 16 + l15;
#pragma unroll
    for (int kk = 0; kk < 8; ++kk)
      uf[f][kk] = *reinterpret_cast<const short8*>(
          &Ut[(size_t)col * 256 + kk * 32 + l4 * 8]);
#pragma unroll
    for (int kk = 0; kk < 4; ++kk)
      wf[f][kk] = *reinterpret_cast<const short8*>(
          &Wt[col * 128 + kk * 32 + l4 * 8]);
    bz[f] = bias[col];
  }

  __syncthreads();

  for (int t = 0; t < 64; ++t) {
    // --- phase 1: z = x@W + h@U + b (B-frags all in registers) ---
    f32x4 acc[2];
    acc[0] = (f32x4){bz[0], bz[0], bz[0], bz[0]};
    acc[1] = (f32x4){bz[1], bz[1], bz[1], bz[1]};
#pragma unroll
    for (int kk = 0; kk < 4; ++kk) {
      short8 af = *reinterpret_cast<const short8*>(&Xs[l15][kk * 32 + l4 * 8]);
      acc[0] = __builtin_amdgcn_mfma_f32_16x16x32_bf16(af, wf[0][kk], acc[0], 0, 0, 0);
      acc[1] = __builtin_amdgcn_mfma_f32_16x16x32_bf16(af, wf[1][kk], acc[1], 0, 0, 0);
    }
#pragma unroll
    for (int kk = 0; kk < 8; ++kk) {
      short8 af = *reinterpret_cast<const short8*>(&Hs[l15][kk * 32 + l4 * 8]);
      acc[0] = __builtin_amdgcn_mfma_f32_16x16x32_bf16(af, uf[0][kk], acc[0], 0, 0, 0);
      acc[1] = __builtin_amdgcn_mfma_f32_16x16x32_bf16(af, uf[1][kk], acc[1], 0, 0, 0);
    }
    // write z to Zs: local col = g*64 + m_local
#pragma unroll
    for (int f = 0; f < 2; ++f) {
      const int fi = w * 2 + f;
      const int cl = (fi & 3) * 64 + (fi >> 2) * 16 + l15;
#pragma unroll
      for (int r = 0; r < 4; ++r) Zs[l4 * 4 + r][cl] = acc[f][r];
    }
    __syncthreads();

    // --- phase 2: gate combine (thread = (b, m-pair)), write Hs + HC ---
    {
      int b = tid & 15, mi = tid >> 4;
      float h2a[2], c2a[2];
#pragma unroll
      for (int e = 0; e < 2; ++e) {
        int m = mi * 2 + e;
        float iv = sigm(Zs[b][m]);
        float fv = sigm(Zs[b][64 + m]);
        float gv = tanh_(Zs[b][128 + m]);
        float ov = sigm(Zs[b][192 + m]);
        float c2 = fv * creg[e] + iv * gv;
        creg[e] = c2;
        h2a[e] = ov * tanh_(c2);
        c2a[e] = c2;
      }
      unsigned hp = cvt_pk_bf16(h2a[0], h2a[1]);
      unsigned cp = cvt_pk_bf16(c2a[0], c2a[1]);
      *reinterpret_cast<unsigned*>(&Hs[b][ms * 64 + mi * 2]) = hp;
      size_t rbase = ((size_t)t * 128 + b0 + b) * 512;
      __hip_atomic_store((unsigned*)&HC[rbase + ms * 64 + mi * 2], hp,
                         __ATOMIC_RELAXED, __HIP_MEMORY_SCOPE_AGENT);
      __hip_atomic_store((unsigned*)&HC[rbase + 256 + ms * 64 + mi * 2], cp,
                         __ATOMIC_RELAXED, __HIP_MEMORY_SCOPE_AGENT);
    }
    __threadfence();   // make h2/c2 agent-visible before the flag
    __syncthreads();

    // --- phase 3: flag, spin partners, pull their h2; stage x_{t+1} ---
    if (t < 63) {
      if (tid == 0)
        __hip_atomic_store(&flags[t * 32 + blockIdx.x], FLAG_BASE + t,
                           __ATOMIC_RELEASE, __HIP_MEMORY_SCOPE_AGENT);
      if (tid < 384) {
        int p = tid >> 7;                // 0..2
        int msP = p + (p >= ms);         // partner m-slice
        int rs = tid & 127, row = rs >> 3, seg = rs & 7;
        int pblk = msP * 8 + bg;
        int it = 0;
        while (__hip_atomic_load(&flags[t * 32 + pblk], __ATOMIC_ACQUIRE,
                                 __HIP_MEMORY_SCOPE_AGENT) != FLAG_BASE + t) {
          if (++it > (1 << 22)) break;   // bounded: no hard wedge
          __builtin_amdgcn_s_sleep(1);
        }
        u64 v = __hip_atomic_load(
            (const u64*)&HC[((size_t)t * 128 + b0 + row) * 512 + msP * 64 + seg * 8],
            __ATOMIC_RELAXED, __HIP_MEMORY_SCOPE_AGENT);
        *reinterpret_cast<u64*>(&Hs[row][msP * 64 + seg * 8]) = v;
      } else {
        int j = tid - 384;               // 0..127: stage x_{t+1}
        int row = j >> 3, seg = j & 7;
        const float4* p = reinterpret_cast<const float4*>(
            &data[(size_t)(b0 + row) * 8192 + (t + 1) * 128 + seg * 16]);
        float4 a0 = p[0], a1 = p[1], a2 = p[2], a3 = p[3];
        *reinterpret_cast<short8*>(&Xs[row][seg * 16]) = pack8(a0, a1);
        *reinterpret_cast<short8*>(&Xs[row][seg * 16 + 8]) = pack8(a2, a3);
      }
    }
    __syncthreads();
  }
}

// ---------------------------------------------------------------------------
// Deferred q: QS[t*128+b][s] = [h2|c2] @ w2_k + w2_b.  Grid 512 x 1 wave;
// block handles 16 consecutive (t*128+b) rows (same t).
// ---------------------------------------------------------------------------
__global__ __launch_bounds__(64) void k_qs(
    const u16* __restrict__ HC, const u16* __restrict__ w2t,
    const float* __restrict__ w2b, float* __restrict__ QS) {
  const int lane = threadIdx.x;
  const int l15 = lane & 15, l4 = lane >> 4;
  const int rbase = blockIdx.x * 16;
  f32x4 qa[4];
#pragma unroll
  for (int sf = 0; sf < 4; ++sf) {
    float bv = w2b[sf * 16 + l15];
    qa[sf] = (f32x4){bv, bv, bv, bv};
  }
#pragma unroll
  for (int kk = 0; kk < 16; ++kk) {
    short8 af = *reinterpret_cast<const short8*>(
        &HC[((size_t)rbase + l15) * 512 + kk * 32 + l4 * 8]);
#pragma unroll
    for (int sf = 0; sf < 4; ++sf) {
      short8 bf = *reinterpret_cast<const short8*>(
          &w2t[(sf * 16 + l15) * 512 + kk * 32 + l4 * 8]);
      qa[sf] = __builtin_amdgcn_mfma_f32_16x16x32_bf16(af, bf, qa[sf], 0, 0, 0);
    }
  }
#pragma unroll
  for (int sf = 0; sf < 4; ++sf)
#pragma unroll
    for (int r = 0; r < 4; ++r)
      QS[((size_t)rbase + l4 * 4 + r) * 64 + sf * 16 + l15] = qa[sf][r];
}

// ---------------------------------------------------------------------------
// Phase B: attention (identical to the measured v2 version).
// out_flat[P*128+f] = data_flat[P*128+f] * alpha(t=P>>7, b=P&127), P=t*128+b.
// ---------------------------------------------------------------------------
__global__ __launch_bounds__(256) void k_attn(
    const float* __restrict__ data, const float* __restrict__ w1k,
    const float* __restrict__ w1b, const float* __restrict__ vk,
    const float* __restrict__ vb, const float* __restrict__ QS,
    float* __restrict__ out) {
  __shared__ float Xs[64][128];
  __shared__ float Wk[64][64];
  __shared__ float w1x[128][66];
  __shared__ float vls[64];
  __shared__ float qls[2][64];
  __shared__ float red[4][2];

  const int tid = threadIdx.x;
  const int b = blockIdx.x >> 1;
  const int half = blockIdx.x & 1;

#pragma unroll
  for (int c = 0; c < 8; ++c) {
    int i = c * 1024 + tid * 4;
    *reinterpret_cast<float4*>(&Xs[0][0] + i) =
        *reinterpret_cast<const float4*>(&data[(size_t)b * 8192 + i]);
  }
#pragma unroll
  for (int c = 0; c < 4; ++c) {
    int i = c * 1024 + tid * 4;
    *reinterpret_cast<float4*>(&Wk[0][0] + i) =
        *reinterpret_cast<const float4*>(&w1k[i]);
  }
  if (tid < 64) vls[tid] = vk[tid];
  __syncthreads();

  const int f = tid & 127;
  const int sh = tid >> 7;
  const int s0 = sh * 32;
  {
    float a[32];
#pragma unroll
    for (int j = 0; j < 32; ++j) a[j] = w1b[s0 + j];
    for (int t = 0; t < 64; ++t) {
      float xv = Xs[t][f];
#pragma unroll
      for (int j = 0; j < 32; ++j) a[j] = __fmaf_rn(xv, Wk[t][s0 + j], a[j]);
    }
#pragma unroll
    for (int j = 0; j < 32; ++j) w1x[f][s0 + j] = a[j];
  }
  __syncthreads();

  const float vbv = vb[0];
  const int wv = tid >> 6;
  const int lane = tid & 63;

  for (int tt = 0; tt < 16; ++tt) {
    if (tid < 128) {
      int which = tid >> 6, s = tid & 63;
      qls[which][s] =
          QS[(size_t)((half * 32 + tt * 2 + which) * 128 + b) * 64 + s];
    }
    __syncthreads();

    float acc = vbv;
#pragma unroll 8
    for (int s = 0; s < 64; ++s)
      acc += tanh_(w1x[f][s] + qls[sh][s]) * vls[s];

    float m = acc;
#pragma unroll
    for (int o = 32; o > 0; o >>= 1) m = fmaxf(m, __shfl_xor(m, o));
    if (lane == 0) red[wv][0] = m;
    __syncthreads();
    m = fmaxf(red[sh * 2][0], red[sh * 2 + 1][0]);
    float e = __expf(acc - m);
    float sum = e;
#pragma unroll
    for (int o = 32; o > 0; o >>= 1) sum += __shfl_xor(sum, o);
    if (lane == 0) red[wv][1] = sum;
    __syncthreads();
    sum = red[sh * 2][1] + red[sh * 2 + 1][1];
    float alpha = e / sum;

    int t = half * 32 + tt * 2 + sh;
    size_t P = (size_t)t * 128 + b;
    out[P * 128 + f] = data[P * 128 + f] * alpha;
    __syncthreads();
  }
}

// ---------------------------------------------------------------------------
extern "C" void kernel_launch(void* const* d_in, const int* in_sizes, int n_in,
                              void* d_out, int out_size, void* d_ws,
                              size_t ws_size, hipStream_t stream) {
  (void)in_sizes; (void)n_in; (void)out_size; (void)ws_size;
  const float* data = (const float*)d_in[0];
  const float* h0   = (const float*)d_in[1];
  const float* c0   = (const float*)d_in[2];
  const float* W    = (const float*)d_in[3];
  const float* U    = (const float*)d_in[4];
  const float* bias = (const float*)d_in[5];
  const float* w1k  = (const float*)d_in[6];
  const float* w1b  = (const float*)d_in[7];
  const float* w2k  = (const float*)d_in[8];
  const float* w2b  = (const float*)d_in[9];
  const float* vk   = (const float*)d_in[10];
  const float* vb   = (const float*)d_in[11];
  float* out = (float*)d_out;

  char* ws = (char*)d_ws;
  u16* Ut    = (u16*)(ws);                  // 512 KB
  u16* Wt    = (u16*)(ws + 524288);         // 256 KB
  u16* w2t   = (u16*)(ws + 786432);         //  64 KB
  int* flags = (int*)(ws + 851968);         //   8 KB (value-tagged; 0xAA-safe)
  float* QS  = (float*)(ws + (1u << 20));   //   2 MB
  u16* HC    = (u16*)(ws + (3u << 20));     //   8 MB  [t][b][h2|c2] bf16

  k_prep<<<512, 256, 0, stream>>>(W, U, w2k, Wt, Ut, w2t);
  k_scan<<<32, 512, 0, stream>>>(data, h0, c0, bias, Wt, Ut, HC, flags);
  k_qs<<<512, 64, 0, stream>>>(HC, w2t, w2b, QS);
  k_attn<<<256, 256, 0, stream>>>(data, w1k, w1b, vk, vb, QS, out);
}